// Round 2
// baseline (2771.503 us; speedup 1.0000x reference)
//
#include <hip/hip_runtime.h>
#include <hip/hip_bf16.h>
#include <stdint.h>

#define B_ 32
#define S_ 2048
#define H_ 1024
#define U_ 1024

typedef __attribute__((ext_vector_type(8))) short short8;
typedef __attribute__((ext_vector_type(4))) float f32x4;

__device__ __forceinline__ unsigned short f2bf(float f) {
  unsigned int u = __float_as_uint(f);
  u += 0x7fffu + ((u >> 16) & 1u);   // RNE
  return (unsigned short)(u >> 16);
}

// ---------- prep 1: W1 [H][U] f32 -> W1T [U][H] bf16 ----------
__global__ void k_transpose_w1(const float* __restrict__ W1, unsigned short* __restrict__ W1T) {
  __shared__ float tile[64][65];
  const int tx = threadIdx.x, ty = threadIdx.y;
  const int u0 = blockIdx.x * 64, h0 = blockIdx.y * 64;
#pragma unroll
  for (int i = 0; i < 16; ++i) {
    int hl = ty + i * 4;
    tile[hl][tx] = W1[(size_t)(h0 + hl) * U_ + (u0 + tx)];
  }
  __syncthreads();
#pragma unroll
  for (int i = 0; i < 16; ++i) {
    int ul = ty + i * 4;
    W1T[(size_t)(u0 + ul) * H_ + (h0 + tx)] = f2bf(tile[tx][ul]);
  }
}

// ---------- prep 2: b1q[b][u] = b1[u] + b2[u] + sum_h query[b][h]*W2[h][u] ----------
__global__ void k_b1q(const float* __restrict__ query, const float* __restrict__ W2,
                      const float* __restrict__ b1, const float* __restrict__ b2,
                      float* __restrict__ b1q) {
  const int b = blockIdx.y;
  const int u = blockIdx.x * 256 + threadIdx.x;
  float acc = b1[u] + b2[u];
  const float* q = query + b * H_;
#pragma unroll 8
  for (int h = 0; h < H_; ++h) acc += q[h] * W2[(size_t)h * U_ + u];
  b1q[b * U_ + u] = acc;
}

// ---------- fused: score_part[bn][b*S+s] = sum_{u in chunk bn} tanh(values@W1 + b1q) * V[u] ----------
#define BM 128
#define BN 512
#define BK 32
#define NT (H_ / BK)

// LDS: As dbuf 2x[128][32]bf16 = 16 KB, Bs single [512][32]bf16 = 32 KB -> 48 KB -> 3 blocks/CU.
// All tiles stored as 64-B rows of four 16-B chunks; chunk q of row r lives at q ^ ((r>>1)&3)
// (XOR swizzle -> fragment ds_read_b128 columns spread across all 8 bank-quads).
__global__ __launch_bounds__(512, 6)
void k_fused_score(const float* __restrict__ values, const unsigned short* __restrict__ W1T,
                   const float* __restrict__ b1q, const float* __restrict__ V,
                   float* __restrict__ score_part) {
  __shared__ __align__(16) unsigned char smem[49152];
  unsigned short* As = (unsigned short*)smem;             // [2][128*32]
  unsigned short* Bs = (unsigned short*)(smem + 16384);   // [512*32]
  float* scorebuf = (float*)smem;                          // alias, used post-loop

  const int tid = threadIdx.x;
  // XCD-aware swizzle: (bm, bn=0/1) pairs adjacent on one XCD -> share values A-tile in L2.
  const int swz = blockIdx.x;
  const int seq = (swz & 7) * 128 + (swz >> 3);
  const int bn = seq & 1;
  const int bm = seq >> 1;

  const int lane = tid & 63, wid = tid >> 6;
  const int wm = wid >> 2, wn = wid & 3;

  // A staging: thread -> (row arow, chunk-pair aq); 2x float4 f32 -> 8 bf16 -> swizzled ds_write_b128
  const int arow = tid >> 2, aq = tid & 3;
  const float* aptr = values + (size_t)(bm * BM + arow) * H_ + aq * 8;
  const int awoff = arow * 32 + (((aq ^ ((arow >> 1) & 3))) << 3);   // shorts

  // B staging (gl_lds, linear dest): phys chunk p = (wid*4+i)*64+lane; n = p>>2;
  // logical k-chunk = (p&3) ^ ((n>>1)&3) -> pre-swizzled global source.
  const int bq = (lane & 3) ^ ((lane >> 3) & 3);
  const int u0 = bn * BN;

  // fragment read swizzle: chunk = (lane>>4) ^ ((row>>1)&3); row ≡ lane&15 (mod 16-chunks)
  const int fsq = (((lane >> 4) ^ ((lane >> 1) & 3)) << 3);          // shorts

  f32x4 acc[4][8];
#pragma unroll
  for (int mf = 0; mf < 4; ++mf)
#pragma unroll
    for (int nf = 0; nf < 8; ++nf) acc[mf][nf] = (f32x4){0.f, 0.f, 0.f, 0.f};

  float4 av0, av1;

  // ---- prologue: stage tile 0 ----
  {
    const float4* p = (const float4*)aptr;
    av0 = p[0]; av1 = p[1];
  }
#pragma unroll
  for (int i = 0; i < 4; ++i) {
    const int n = (wid * 4 + i) * 16 + (lane >> 2);
    const unsigned short* src = W1T + (size_t)(u0 + n) * H_ + bq * 8;
    __builtin_amdgcn_global_load_lds((const __attribute__((address_space(1))) void*)src,
                                     (__attribute__((address_space(3))) void*)&Bs[(wid * 4 + i) * 512],
                                     16, 0, 0);
  }
  {
    short8 w;
    w[0]=f2bf(av0.x); w[1]=f2bf(av0.y); w[2]=f2bf(av0.z); w[3]=f2bf(av0.w);
    w[4]=f2bf(av1.x); w[5]=f2bf(av1.y); w[6]=f2bf(av1.z); w[7]=f2bf(av1.w);
    *(short8*)&As[awoff] = w;
  }
  __syncthreads();

  int cur = 0;
  for (int kt = 0; kt < NT; ++kt) {
    const bool more = (kt + 1 < NT);
    if (more) {                            // issue A prefetch early (regs)
      const float4* p = (const float4*)(aptr + (kt + 1) * BK);
      av0 = p[0]; av1 = p[1];
    }
    // fragment reads (swizzled, conflict-free)
    short8 af[4], bfr[8];
#pragma unroll
    for (int mf = 0; mf < 4; ++mf) {
      const int row = wm * 64 + mf * 16 + (lane & 15);
      af[mf] = *(const short8*)&As[cur * 4096 + row * 32 + fsq];
    }
#pragma unroll
    for (int nf = 0; nf < 8; ++nf) {
      const int n = wn * 128 + nf * 16 + (lane & 15);
      bfr[nf] = *(const short8*)&Bs[n * 32 + fsq];
    }
    // barrier(1): only LDS reads must drain — keep A-prefetch vmem in flight
    asm volatile("s_waitcnt lgkmcnt(0)" ::: "memory");
    __builtin_amdgcn_sched_barrier(0);
    __builtin_amdgcn_s_barrier();
    __builtin_amdgcn_sched_barrier(0);

    if (more) {                            // restage B (single buffer, now safe)
#pragma unroll
      for (int i = 0; i < 4; ++i) {
        const int n = (wid * 4 + i) * 16 + (lane >> 2);
        const unsigned short* src = W1T + (size_t)(u0 + n) * H_ + (kt + 1) * BK + bq * 8;
        __builtin_amdgcn_global_load_lds((const __attribute__((address_space(1))) void*)src,
                                         (__attribute__((address_space(3))) void*)&Bs[(wid * 4 + i) * 512],
                                         16, 0, 0);
      }
    }
#pragma unroll
    for (int nf = 0; nf < 8; ++nf)
#pragma unroll
      for (int mf = 0; mf < 4; ++mf)
        acc[mf][nf] = __builtin_amdgcn_mfma_f32_16x16x32_bf16(af[mf], bfr[nf], acc[mf][nf], 0, 0, 0);
    if (more) {                            // cvt + write next A (latency covered by reads+MFMA)
      short8 w;
      w[0]=f2bf(av0.x); w[1]=f2bf(av0.y); w[2]=f2bf(av0.z); w[3]=f2bf(av0.w);
      w[4]=f2bf(av1.x); w[5]=f2bf(av1.y); w[6]=f2bf(av1.z); w[7]=f2bf(av1.w);
      *(short8*)&As[(cur ^ 1) * 4096 + awoff] = w;
    }
    __syncthreads();                       // barrier(2): drain gl_lds + ds_write
    cur ^= 1;
  }

  // ---- epilogue: tanh(acc + b1q) * V, reduce over u ----
  const int b_blk = bm >> 4;               // 128 rows never cross a batch boundary
  float bqv[8], vv[8];
#pragma unroll
  for (int nf = 0; nf < 8; ++nf) {
    const int ug = u0 + wn * 128 + nf * 16 + (lane & 15);   // D col = lane&15
    bqv[nf] = b1q[b_blk * U_ + ug];
    vv[nf] = V[ug];
  }
  float rp[4][4];
#pragma unroll
  for (int mf = 0; mf < 4; ++mf)
#pragma unroll
    for (int j = 0; j < 4; ++j) rp[mf][j] = 0.f;
#pragma unroll
  for (int nf = 0; nf < 8; ++nf)
#pragma unroll
    for (int mf = 0; mf < 4; ++mf) {
      const f32x4 c = acc[mf][nf];
#pragma unroll
      for (int j = 0; j < 4; ++j) {
        const float x = c[j] + bqv[nf];
        const float e = __expf(2.f * x);   // inf-safe: e=inf -> t=1, e=0 -> t=-1
        const float t = 1.f - 2.f / (e + 1.f);
        rp[mf][j] += t * vv[nf];
      }
    }
#pragma unroll
  for (int mf = 0; mf < 4; ++mf)
#pragma unroll
    for (int j = 0; j < 4; ++j) {
      float v = rp[mf][j];
      v += __shfl_xor(v, 1);
      v += __shfl_xor(v, 2);
      v += __shfl_xor(v, 4);
      v += __shfl_xor(v, 8);
      rp[mf][j] = v;
    }
  if ((lane & 15) == 0) {
#pragma unroll
    for (int mf = 0; mf < 4; ++mf)
#pragma unroll
      for (int j = 0; j < 4; ++j)
        scorebuf[(wm * 64 + mf * 16 + (lane >> 4) * 4 + j) * 4 + wn] = rp[mf][j];
  }
  __syncthreads();
  if (tid < BM) {
    const float s = scorebuf[tid * 4 + 0] + scorebuf[tid * 4 + 1] +
                    scorebuf[tid * 4 + 2] + scorebuf[tid * 4 + 3];
    score_part[(size_t)bn * (B_ * S_) + bm * BM + tid] = s;
  }
}

// ---------- softmax over S per batch (bV is shift-invariant -> dropped) ----------
__global__ void k_softmax(const float* __restrict__ p0, const float* __restrict__ p1,
                          float* __restrict__ aw) {
  __shared__ float red[8];
  const int b = blockIdx.x, tid = threadIdx.x;   // 256 threads, 8 elems each
  float x[8];
  float m = -1e30f;
#pragma unroll
  for (int i = 0; i < 8; ++i) {
    const int s = tid + i * 256;
    x[i] = p0[b * S_ + s] + p1[b * S_ + s];
    m = fmaxf(m, x[i]);
  }
#pragma unroll
  for (int off = 32; off; off >>= 1) m = fmaxf(m, __shfl_xor(m, off));
  if ((tid & 63) == 0) red[tid >> 6] = m;
  __syncthreads();
  m = fmaxf(fmaxf(red[0], red[1]), fmaxf(red[2], red[3]));
  float e[8];
  float sum = 0.f;
#pragma unroll
  for (int i = 0; i < 8; ++i) { e[i] = __expf(x[i] - m); sum += e[i]; }
#pragma unroll
  for (int off = 32; off; off >>= 1) sum += __shfl_xor(sum, off);
  __syncthreads();
  if ((tid & 63) == 0) red[4 + (tid >> 6)] = sum;
  __syncthreads();
  sum = red[4] + red[5] + red[6] + red[7];
  const float inv = 1.f / sum;
#pragma unroll
  for (int i = 0; i < 8; ++i) aw[b * S_ + tid + i * 256] = e[i] * inv;
}

// ---------- context: partial weighted sums over s-chunks, then combine ----------
__global__ void k_ctx_partial(const float* __restrict__ values, const float* __restrict__ aw,
                              float* __restrict__ part) {
  __shared__ float a_s[128];
  const int b = blockIdx.y, sc = blockIdx.x, tid = threadIdx.x;  // 16 chunks x 128 s
  if (tid < 128) a_s[tid] = aw[b * S_ + sc * 128 + tid];
  __syncthreads();
  const float4* vp = (const float4*)values + (size_t)(b * S_ + sc * 128) * (H_ / 4) + tid;
  float4 acc = {0.f, 0.f, 0.f, 0.f};
#pragma unroll 4
  for (int i = 0; i < 128; ++i) {
    const float4 v = vp[(size_t)i * (H_ / 4)];
    const float a = a_s[i];
    acc.x += a * v.x; acc.y += a * v.y; acc.z += a * v.z; acc.w += a * v.w;
  }
  ((float4*)part)[(size_t)(b * 16 + sc) * (H_ / 4) + tid] = acc;
}

__global__ void k_ctx_combine(const float* __restrict__ part, float* __restrict__ ctx) {
  const int b = blockIdx.x, tid = threadIdx.x;
  float4 s = {0.f, 0.f, 0.f, 0.f};
#pragma unroll
  for (int c = 0; c < 16; ++c) {
    const float4 v = ((const float4*)part)[(size_t)(b * 16 + c) * (H_ / 4) + tid];
    s.x += v.x; s.y += v.y; s.z += v.z; s.w += v.w;
  }
  ((float4*)ctx)[b * (H_ / 4) + tid] = s;
}

extern "C" void kernel_launch(void* const* d_in, const int* in_sizes, int n_in,
                              void* d_out, int out_size, void* d_ws, size_t ws_size,
                              hipStream_t stream) {
  const float* query  = (const float*)d_in[0];
  const float* values = (const float*)d_in[1];
  const float* W1     = (const float*)d_in[2];
  const float* b1     = (const float*)d_in[3];
  const float* W2     = (const float*)d_in[4];
  const float* b2     = (const float*)d_in[5];
  const float* V      = (const float*)d_in[6];
  // d_in[7] = bV: softmax shift-invariant, affects neither output -> unused.

  char* ws = (char*)d_ws;
  unsigned short* W1T = (unsigned short*)ws;                                  // 2 MB  [U][H] bf16
  float* b1q   = (float*)(ws + 2u * 1024u * 1024u);                           // 128 KB [B][U]
  float* spart = (float*)(ws + 2u * 1024u * 1024u + 128u * 1024u);            // 512 KB [2][B*S]
  float* cpart = (float*)(ws + 2u * 1024u * 1024u + 128u * 1024u + 512u * 1024u); // 2 MB [B*16][H]

  float* aw  = (float*)d_out;        // [B,S,1]
  float* ctx = aw + B_ * S_;         // [B,H]

  hipLaunchKernelGGL(k_transpose_w1, dim3(16, 16), dim3(64, 4), 0, stream, W1, W1T);
  hipLaunchKernelGGL(k_b1q,          dim3(4, 32),  dim3(256),   0, stream, query, W2, b1, b2, b1q);
  hipLaunchKernelGGL(k_fused_score,  dim3(1024),   dim3(512),   0, stream, values, W1T, b1q, V, spart);
  hipLaunchKernelGGL(k_softmax,      dim3(32),     dim3(256),   0, stream, spart, spart + B_ * S_, aw);
  hipLaunchKernelGGL(k_ctx_partial,  dim3(16, 32), dim3(256),   0, stream, values, aw, cpart);
  hipLaunchKernelGGL(k_ctx_combine,  dim3(32),     dim3(256),   0, stream, cpart, ctx);
}

// Round 3
// 314.117 us; speedup vs baseline: 8.8232x; 8.8232x over previous
//
#include <hip/hip_runtime.h>
#include <hip/hip_bf16.h>
#include <stdint.h>

#define B_ 32
#define S_ 2048
#define H_ 1024
#define U_ 1024

typedef __attribute__((ext_vector_type(8))) short short8;
typedef __attribute__((ext_vector_type(4))) float f32x4;

__device__ __forceinline__ unsigned short f2bf(float f) {
  unsigned int u = __float_as_uint(f);
  u += 0x7fffu + ((u >> 16) & 1u);   // RNE
  return (unsigned short)(u >> 16);
}

// ---------- prep 1: W1 [H][U] f32 -> W1T [U][H] bf16 ----------
__global__ void k_transpose_w1(const float* __restrict__ W1, unsigned short* __restrict__ W1T) {
  __shared__ float tile[64][65];
  const int tx = threadIdx.x, ty = threadIdx.y;
  const int u0 = blockIdx.x * 64, h0 = blockIdx.y * 64;
#pragma unroll
  for (int i = 0; i < 16; ++i) {
    int hl = ty + i * 4;
    tile[hl][tx] = W1[(size_t)(h0 + hl) * U_ + (u0 + tx)];
  }
  __syncthreads();
#pragma unroll
  for (int i = 0; i < 16; ++i) {
    int ul = ty + i * 4;
    W1T[(size_t)(u0 + ul) * H_ + (h0 + tx)] = f2bf(tile[tx][ul]);
  }
}

// ---------- prep 2: b1q[b][u] = b1[u] + b2[u] + sum_h query[b][h]*W2[h][u] ----------
__global__ void k_b1q(const float* __restrict__ query, const float* __restrict__ W2,
                      const float* __restrict__ b1, const float* __restrict__ b2,
                      float* __restrict__ b1q) {
  const int b = blockIdx.y;
  const int u = blockIdx.x * 256 + threadIdx.x;
  float acc = b1[u] + b2[u];
  const float* q = query + b * H_;
#pragma unroll 8
  for (int h = 0; h < H_; ++h) acc += q[h] * W2[(size_t)h * U_ + u];
  b1q[b * U_ + u] = acc;
}

// ---------- fused: score_part[bn][b*S+s] = sum_{u in chunk bn} tanh(values@W1 + b1q) * V[u] ----------
#define BM 128
#define BN 512
#define BK 32
#define NT (H_ / BK)

// LDS: As dbuf 2x[128][32]bf16 = 16 KB, Bs dbuf 2x[512][32]bf16 = 64 KB -> 80 KB static.
// 64-B rows of four 16-B chunks; logical chunk q of row r stored at phys q ^ ((r>>1)&3)
// (XOR swizzle -> fragment ds_read_b128 columns hit all 8 bank-quads; verified 0 conflicts in r2).
// One barrier per K-step: prefetch t+1 at top, compute buf[cur], __syncthreads at end
// (its vmcnt(0) drain sits after ~1240 cyc of MFMA -> load latency covered).
__global__ __launch_bounds__(512, 2)
void k_fused_score(const float* __restrict__ values, const unsigned short* __restrict__ W1T,
                   const float* __restrict__ b1q, const float* __restrict__ V,
                   float* __restrict__ score_part) {
  __shared__ __align__(16) unsigned char smem[81920];
  unsigned short* As = (unsigned short*)smem;             // [2][128*32]
  unsigned short* Bs = (unsigned short*)(smem + 16384);   // [2][512*32]
  float* scorebuf = (float*)smem;                          // alias, used post-loop

  const int tid = threadIdx.x;
  // XCD-aware swizzle: (bm, bn=0/1) pairs adjacent in time on one XCD -> share values panel in L2.
  const int swz = blockIdx.x;
  const int seq = (swz & 7) * 128 + (swz >> 3);
  const int bn = seq & 1;
  const int bm = seq >> 1;

  const int lane = tid & 63, wid = tid >> 6;
  const int wm = wid >> 2, wn = wid & 3;

  // A staging: thread -> (row arow, chunk aq); 2x float4 f32 -> 8 bf16 -> swizzled ds_write_b128
  const int arow = tid >> 2, aq = tid & 3;
  const float* aptr = values + (size_t)(bm * BM + arow) * H_ + aq * 8;
  const int awoff = arow * 32 + ((aq ^ ((arow >> 1) & 3)) << 3);   // shorts

  // B staging (gl_lds, linear dest): phys chunk p = (wid*4+i)*64+lane; row n = p>>2;
  // logical k-chunk at that phys slot = (p&3) ^ ((n>>1)&3) -> pre-swizzled global source.
  const int bq = (lane & 3) ^ ((lane >> 3) & 3);
  const int u0 = bn * BN;

  // fragment read swizzle: phys chunk = (lane>>4) ^ ((row>>1)&3), row ≡ lane&15 (bases mult. of 16)
  const int fsq = (((lane >> 4) ^ ((lane >> 1) & 3)) << 3);        // shorts

  f32x4 acc[4][8];
#pragma unroll
  for (int mf = 0; mf < 4; ++mf)
#pragma unroll
    for (int nf = 0; nf < 8; ++nf) acc[mf][nf] = (f32x4){0.f, 0.f, 0.f, 0.f};

  // ---- prologue: stage tile 0 into buf 0 ----
  {
    const float4* p = (const float4*)aptr;
    float4 av0 = p[0], av1 = p[1];
#pragma unroll
    for (int i = 0; i < 4; ++i) {
      const int n = (wid * 4 + i) * 16 + (lane >> 2);
      const unsigned short* src = W1T + (size_t)(u0 + n) * H_ + bq * 8;
      __builtin_amdgcn_global_load_lds((const __attribute__((address_space(1))) void*)src,
                                       (__attribute__((address_space(3))) void*)&Bs[(wid * 4 + i) * 512],
                                       16, 0, 0);
    }
    short8 w;
    w[0]=f2bf(av0.x); w[1]=f2bf(av0.y); w[2]=f2bf(av0.z); w[3]=f2bf(av0.w);
    w[4]=f2bf(av1.x); w[5]=f2bf(av1.y); w[6]=f2bf(av1.z); w[7]=f2bf(av1.w);
    *(short8*)&As[awoff] = w;
  }
  __syncthreads();

  int cur = 0;
  for (int kt = 0; kt < NT; ++kt) {
    const bool more = (kt + 1 < NT);
    float4 av0, av1;
    if (more) {                            // issue prefetch for t+1 (A -> regs, B -> LDS[cur^1])
      const float4* p = (const float4*)(aptr + (kt + 1) * BK);
      av0 = p[0]; av1 = p[1];
#pragma unroll
      for (int i = 0; i < 4; ++i) {
        const int n = (wid * 4 + i) * 16 + (lane >> 2);
        const unsigned short* src = W1T + (size_t)(u0 + n) * H_ + (kt + 1) * BK + bq * 8;
        __builtin_amdgcn_global_load_lds((const __attribute__((address_space(1))) void*)src,
                                         (__attribute__((address_space(3))) void*)&Bs[(cur ^ 1) * 16384 + (wid * 4 + i) * 512],
                                         16, 0, 0);
      }
    }
    // fragment reads from buf[cur] (swizzled, conflict-free)
    short8 af[4], bfr[8];
#pragma unroll
    for (int mf = 0; mf < 4; ++mf) {
      const int row = wm * 64 + mf * 16 + (lane & 15);
      af[mf] = *(const short8*)&As[cur * 4096 + row * 32 + fsq];
    }
#pragma unroll
    for (int nf = 0; nf < 8; ++nf) {
      const int n = wn * 128 + nf * 16 + (lane & 15);
      bfr[nf] = *(const short8*)&Bs[cur * 16384 + n * 32 + fsq];
    }
#pragma unroll
    for (int nf = 0; nf < 8; ++nf)
#pragma unroll
      for (int mf = 0; mf < 4; ++mf)
        acc[mf][nf] = __builtin_amdgcn_mfma_f32_16x16x32_bf16(af[mf], bfr[nf], acc[mf][nf], 0, 0, 0);
    if (more) {                            // cvt + write next A (A-load latency hidden by MFMA)
      short8 w;
      w[0]=f2bf(av0.x); w[1]=f2bf(av0.y); w[2]=f2bf(av0.z); w[3]=f2bf(av0.w);
      w[4]=f2bf(av1.x); w[5]=f2bf(av1.y); w[6]=f2bf(av1.z); w[7]=f2bf(av1.w);
      *(short8*)&As[(cur ^ 1) * 4096 + awoff] = w;
    }
    __syncthreads();                       // single barrier/step: drains gl_lds + ds_write
    cur ^= 1;
  }

  // ---- epilogue: tanh(acc + b1q) * V, reduce over u ----
  const int b_blk = bm >> 4;               // 128 rows never cross a batch boundary
  float bqv[8], vv[8];
#pragma unroll
  for (int nf = 0; nf < 8; ++nf) {
    const int ug = u0 + wn * 128 + nf * 16 + (lane & 15);   // D col = lane&15
    bqv[nf] = b1q[b_blk * U_ + ug];
    vv[nf] = V[ug];
  }
  float rp[4][4];
#pragma unroll
  for (int mf = 0; mf < 4; ++mf)
#pragma unroll
    for (int j = 0; j < 4; ++j) rp[mf][j] = 0.f;
#pragma unroll
  for (int nf = 0; nf < 8; ++nf)
#pragma unroll
    for (int mf = 0; mf < 4; ++mf) {
      const f32x4 c = acc[mf][nf];
#pragma unroll
      for (int j = 0; j < 4; ++j) {
        const float x = c[j] + bqv[nf];
        const float e = __expf(2.f * x);   // inf-safe: e=inf -> t=1, e=0 -> t=-1
        const float t = 1.f - 2.f / (e + 1.f);
        rp[mf][j] += t * vv[nf];
      }
    }
#pragma unroll
  for (int mf = 0; mf < 4; ++mf)
#pragma unroll
    for (int j = 0; j < 4; ++j) {
      float v = rp[mf][j];
      v += __shfl_xor(v, 1);
      v += __shfl_xor(v, 2);
      v += __shfl_xor(v, 4);
      v += __shfl_xor(v, 8);
      rp[mf][j] = v;
    }
  if ((lane & 15) == 0) {
#pragma unroll
    for (int mf = 0; mf < 4; ++mf)
#pragma unroll
      for (int j = 0; j < 4; ++j)
        scorebuf[(wm * 64 + mf * 16 + (lane >> 4) * 4 + j) * 4 + wn] = rp[mf][j];
  }
  __syncthreads();
  if (tid < BM) {
    const float s = scorebuf[tid * 4 + 0] + scorebuf[tid * 4 + 1] +
                    scorebuf[tid * 4 + 2] + scorebuf[tid * 4 + 3];
    score_part[(size_t)bn * (B_ * S_) + bm * BM + tid] = s;
  }
}

// ---------- softmax over S per batch (bV is shift-invariant -> dropped) ----------
__global__ void k_softmax(const float* __restrict__ p0, const float* __restrict__ p1,
                          float* __restrict__ aw) {
  __shared__ float red[8];
  const int b = blockIdx.x, tid = threadIdx.x;   // 256 threads, 8 elems each
  float x[8];
  float m = -1e30f;
#pragma unroll
  for (int i = 0; i < 8; ++i) {
    const int s = tid + i * 256;
    x[i] = p0[b * S_ + s] + p1[b * S_ + s];
    m = fmaxf(m, x[i]);
  }
#pragma unroll
  for (int off = 32; off; off >>= 1) m = fmaxf(m, __shfl_xor(m, off));
  if ((tid & 63) == 0) red[tid >> 6] = m;
  __syncthreads();
  m = fmaxf(fmaxf(red[0], red[1]), fmaxf(red[2], red[3]));
  float e[8];
  float sum = 0.f;
#pragma unroll
  for (int i = 0; i < 8; ++i) { e[i] = __expf(x[i] - m); sum += e[i]; }
#pragma unroll
  for (int off = 32; off; off >>= 1) sum += __shfl_xor(sum, off);
  __syncthreads();
  if ((tid & 63) == 0) red[4 + (tid >> 6)] = sum;
  __syncthreads();
  sum = red[4] + red[5] + red[6] + red[7];
  const float inv = 1.f / sum;
#pragma unroll
  for (int i = 0; i < 8; ++i) aw[b * S_ + tid + i * 256] = e[i] * inv;
}

// ---------- context: partial weighted sums over s-chunks, then combine ----------
__global__ void k_ctx_partial(const float* __restrict__ values, const float* __restrict__ aw,
                              float* __restrict__ part) {
  __shared__ float a_s[128];
  const int b = blockIdx.y, sc = blockIdx.x, tid = threadIdx.x;  // 16 chunks x 128 s
  if (tid < 128) a_s[tid] = aw[b * S_ + sc * 128 + tid];
  __syncthreads();
  const float4* vp = (const float4*)values + (size_t)(b * S_ + sc * 128) * (H_ / 4) + tid;
  float4 acc = {0.f, 0.f, 0.f, 0.f};
#pragma unroll 4
  for (int i = 0; i < 128; ++i) {
    const float4 v = vp[(size_t)i * (H_ / 4)];
    const float a = a_s[i];
    acc.x += a * v.x; acc.y += a * v.y; acc.z += a * v.z; acc.w += a * v.w;
  }
  ((float4*)part)[(size_t)(b * 16 + sc) * (H_ / 4) + tid] = acc;
}

__global__ void k_ctx_combine(const float* __restrict__ part, float* __restrict__ ctx) {
  const int b = blockIdx.x, tid = threadIdx.x;
  float4 s = {0.f, 0.f, 0.f, 0.f};
#pragma unroll
  for (int c = 0; c < 16; ++c) {
    const float4 v = ((const float4*)part)[(size_t)(b * 16 + c) * (H_ / 4) + tid];
    s.x += v.x; s.y += v.y; s.z += v.z; s.w += v.w;
  }
  ((float4*)ctx)[b * (H_ / 4) + tid] = s;
}

extern "C" void kernel_launch(void* const* d_in, const int* in_sizes, int n_in,
                              void* d_out, int out_size, void* d_ws, size_t ws_size,
                              hipStream_t stream) {
  const float* query  = (const float*)d_in[0];
  const float* values = (const float*)d_in[1];
  const float* W1     = (const float*)d_in[2];
  const float* b1     = (const float*)d_in[3];
  const float* W2     = (const float*)d_in[4];
  const float* b2     = (const float*)d_in[5];
  const float* V      = (const float*)d_in[6];
  // d_in[7] = bV: softmax shift-invariant, affects neither output -> unused.

  char* ws = (char*)d_ws;
  unsigned short* W1T = (unsigned short*)ws;                                  // 2 MB  [U][H] bf16
  float* b1q   = (float*)(ws + 2u * 1024u * 1024u);                           // 128 KB [B][U]
  float* spart = (float*)(ws + 2u * 1024u * 1024u + 128u * 1024u);            // 512 KB [2][B*S]
  float* cpart = (float*)(ws + 2u * 1024u * 1024u + 128u * 1024u + 512u * 1024u); // 2 MB [B*16][H]

  float* aw  = (float*)d_out;        // [B,S,1]
  float* ctx = aw + B_ * S_;         // [B,H]

  hipLaunchKernelGGL(k_transpose_w1, dim3(16, 16), dim3(64, 4), 0, stream, W1, W1T);
  hipLaunchKernelGGL(k_b1q,          dim3(4, 32),  dim3(256),   0, stream, query, W2, b1, b2, b1q);
  hipLaunchKernelGGL(k_fused_score,  dim3(1024),   dim3(512),   0, stream, values, W1T, b1q, V, spart);
  hipLaunchKernelGGL(k_softmax,      dim3(32),     dim3(256),   0, stream, spart, spart + B_ * S_, aw);
  hipLaunchKernelGGL(k_ctx_partial,  dim3(16, 32), dim3(256),   0, stream, values, aw, cpart);
  hipLaunchKernelGGL(k_ctx_combine,  dim3(32),     dim3(256),   0, stream, cpart, ctx);
}